// Round 1
// baseline (700.797 us; speedup 1.0000x reference)
//
#include <hip/hip_runtime.h>
#include <math.h>

namespace {
constexpr int kH = 384, kW = 384, kBn = 2;
constexpr int kHW = kH * kW;     // 147456
constexpr int kOMD = 112;
}

__device__ __forceinline__ void fma4(float* acc, float a, float4 w) {
    acc[0] = fmaf(a, w.x, acc[0]);
    acc[1] = fmaf(a, w.y, acc[1]);
    acc[2] = fmaf(a, w.z, acc[2]);
    acc[3] = fmaf(a, w.w, acc[3]);
}

// K1: value[b,h,w,c] = sum_ci inp[b,ci,h,w] * Wv[ci,c] + bv[c]
__global__ __launch_bounds__(256) void k_value(
        const float* __restrict__ inp, const float* __restrict__ Wv,
        const float* __restrict__ bv, float* __restrict__ value) {
    __shared__ float xin[64][64];   // [ci][p]
    __shared__ float wv[64 * 64];   // [ci][co]
    const int tid = threadIdx.x;
    const int bid = blockIdx.x;
    const int b = bid / (kHW / 64);
    const int pix0 = (bid % (kHW / 64)) * 64;
    const float* ib = inp + (size_t)b * 64 * kHW + pix0;
    for (int i = tid; i < 4096; i += 256) {
        const int c = i >> 6, p = i & 63;
        xin[c][p] = ib[(size_t)c * kHW + p];
        wv[i] = Wv[i];
    }
    __syncthreads();
    const int p = tid & 63, cg = tid >> 6;
    float acc[16];
    #pragma unroll
    for (int j = 0; j < 16; ++j) acc[j] = bv[cg * 16 + j];
    #pragma unroll 4
    for (int ci = 0; ci < 64; ++ci) {
        const float a = xin[ci][p];
        const float4* wr = (const float4*)&wv[ci * 64 + cg * 16];
        fma4(acc + 0, a, wr[0]);
        fma4(acc + 4, a, wr[1]);
        fma4(acc + 8, a, wr[2]);
        fma4(acc + 12, a, wr[3]);
    }
    float4* vo = (float4*)(value + ((size_t)b * kHW + pix0 + p) * 64 + cg * 16);
    vo[0] = make_float4(acc[0], acc[1], acc[2], acc[3]);
    vo[1] = make_float4(acc[4], acc[5], acc[6], acc[7]);
    vo[2] = make_float4(acc[8], acc[9], acc[10], acc[11]);
    vo[3] = make_float4(acc[12], acc[13], acc[14], acc[15]);
}

// K2: fused depthwise conv -> om matvec -> deformable sampling -> @Wo -> out
// One block = 64 consecutive pixels of one row (b, h, w0..w0+63), 256 threads.
__global__ __launch_bounds__(256) void k_main(
        const float* __restrict__ inp, const float* __restrict__ Wdw,
        const float* __restrict__ bdw, const float* __restrict__ Wom,
        const float* __restrict__ bom, const float* __restrict__ Wo,
        const float* __restrict__ value, float* __restrict__ out) {
    __shared__ float lds1[64][68];   // dw^T [c][p]; later reused as out^T [c][p]
    __shared__ float woS[64 * 64];   // Wo staging [ci][co]
    __shared__ float omp[64][109];   // om per pixel [p][o], o<108

    const int tid = threadIdx.x;
    const int bid = blockIdx.x;
    const int b = bid / (kH * (kW / 64));
    const int rem = bid % (kH * (kW / 64));
    const int h = rem / (kW / 64);
    const int w0 = (rem % (kW / 64)) * 64;

    // ---- stage A: depthwise 3x3 conv (zero pad) -> lds1[c][p] ----
    {
        const int p = tid & 63, cg = tid >> 6;
        const int w = w0 + p;
        for (int cc = 0; cc < 16; ++cc) {
            const int c = cg * 16 + cc;
            const float* ib = inp + (size_t)(b * 64 + c) * kHW;
            float s = bdw[c];
            #pragma unroll
            for (int r = 0; r < 3; ++r) {
                const int y = h - 1 + r;
                if (y >= 0 && y < kH) {
                    const float* rowp = ib + (size_t)y * kW;
                    #pragma unroll
                    for (int kx = 0; kx < 3; ++kx) {
                        const int x = w - 1 + kx;
                        const float v = (x >= 0 && x < kW) ? rowp[x] : 0.f;
                        s = fmaf(v, Wdw[c * 9 + r * 3 + kx], s);
                    }
                }
            }
            lds1[c][p] = s;
        }
    }
    __syncthreads();

    // ---- stage B: om[p][o] = sum_ci dw[p][ci]*Wom[ci][o] + bom[o] ----
    // thread (tp,to): 4 pixels (tp*4..) x 7 outputs (to*7..), covers o in [0,112)
    {
        const int tp = tid & 15, to = tid >> 4;
        float acc[4][7];
        #pragma unroll
        for (int j = 0; j < 7; ++j) {
            const float bj = bom[to * 7 + j];
            acc[0][j] = bj; acc[1][j] = bj; acc[2][j] = bj; acc[3][j] = bj;
        }
        for (int ci = 0; ci < 64; ++ci) {
            const float4 d4 = *(const float4*)&lds1[ci][tp * 4];
            const float* wr = Wom + ci * kOMD + to * 7;
            #pragma unroll
            for (int j = 0; j < 7; ++j) {
                const float wj = wr[j];
                acc[0][j] = fmaf(d4.x, wj, acc[0][j]);
                acc[1][j] = fmaf(d4.y, wj, acc[1][j]);
                acc[2][j] = fmaf(d4.z, wj, acc[2][j]);
                acc[3][j] = fmaf(d4.w, wj, acc[3][j]);
            }
        }
        #pragma unroll
        for (int q = 0; q < 4; ++q) {
            #pragma unroll
            for (int j = 0; j < 7; ++j) {
                const int o = to * 7 + j;
                if (o < 108) omp[tp * 4 + q][o] = acc[q][j];
            }
        }
    }
    __syncthreads();

    // ---- Wo staging (overlaps with sampling) ----
    for (int i = tid; i < 4096; i += 256) woS[i] = Wo[i];

    // ---- stage C: deformable bilinear sampling, thread (p, g) ----
    {
        const int p = tid & 63, g = tid >> 6;
        float acc[16];
        #pragma unroll
        for (int j = 0; j < 16; ++j) acc[j] = 0.f;
        const float fw = (float)(w0 + p);
        const float fh = (float)h;
        const float* omr = &omp[p][g * 27];
        #pragma unroll 1
        for (int k = 0; k < 9; ++k) {
            const int ky = k / 3, kx = k % 3;
            const float dx = omr[2 * k];
            const float dy = omr[2 * k + 1];
            const float m = omr[18 + k];
            const float px = fw + (float)(kx - 1) + dx;
            const float py = fh + (float)(ky - 1) + dy;
            const float x0f = floorf(px), y0f = floorf(py);
            const int x0 = (int)x0f, y0 = (int)y0f;
            const float wx1 = px - x0f, wy1 = py - y0f;
            const float wx0 = 1.f - wx1, wy0 = 1.f - wy1;
            #pragma unroll
            for (int cor = 0; cor < 4; ++cor) {
                const int dy2 = cor >> 1, dx2 = cor & 1;
                const int xi = x0 + dx2, yi = y0 + dy2;
                float wgt = (dy2 ? wy1 : wy0) * (dx2 ? wx1 : wx0) * m;
                if (xi < 0 || xi >= kW || yi < 0 || yi >= kH) wgt = 0.f;
                const int xc = min(max(xi, 0), kW - 1);
                const int yc = min(max(yi, 0), kH - 1);
                const float4* vp = (const float4*)(value +
                        ((size_t)b * kHW + (size_t)yc * kW + xc) * 64 + g * 16);
                fma4(acc + 0, wgt, vp[0]);
                fma4(acc + 4, wgt, vp[1]);
                fma4(acc + 8, wgt, vp[2]);
                fma4(acc + 12, wgt, vp[3]);
            }
        }
        // write sampled result transposed into lds1 (dw is dead now)
        #pragma unroll
        for (int j = 0; j < 16; ++j) lds1[g * 16 + j][p] = acc[j];
    }
    __syncthreads();

    // ---- stage D: final @Wo, coalesced (B,C,H,W) writeout ----
    {
        const int p = tid & 63, cg = tid >> 6;
        float acc[16];
        #pragma unroll
        for (int j = 0; j < 16; ++j) acc[j] = 0.f;
        #pragma unroll 4
        for (int ci = 0; ci < 64; ++ci) {
            const float a = lds1[ci][p];
            const float4* wr = (const float4*)&woS[ci * 64 + cg * 16];
            fma4(acc + 0, a, wr[0]);
            fma4(acc + 4, a, wr[1]);
            fma4(acc + 8, a, wr[2]);
            fma4(acc + 12, a, wr[3]);
        }
        float* ob = out + (size_t)(b * 64 + cg * 16) * kHW + (size_t)h * kW + w0 + p;
        #pragma unroll
        for (int j = 0; j < 16; ++j) ob[(size_t)j * kHW] = acc[j];
    }
}

extern "C" void kernel_launch(void* const* d_in, const int* in_sizes, int n_in,
                              void* d_out, int out_size, void* d_ws, size_t ws_size,
                              hipStream_t stream) {
    const float* inp = (const float*)d_in[0];
    const float* Wv  = (const float*)d_in[1];
    const float* bv  = (const float*)d_in[2];
    const float* Wdw = (const float*)d_in[3];
    const float* bdw = (const float*)d_in[4];
    const float* Wom = (const float*)d_in[5];
    const float* bom = (const float*)d_in[6];
    const float* Wo  = (const float*)d_in[7];
    float* outp  = (float*)d_out;
    float* value = (float*)d_ws;    // (B,H,W,64) fp32 = 75.5 MB

    const int nblk = kBn * (kHW / 64);   // 4608
    k_value<<<nblk, 256, 0, stream>>>(inp, Wv, bv, value);
    k_main<<<nblk, 256, 0, stream>>>(inp, Wdw, bdw, Wom, bom, Wo, value, outp);
}

// Round 2
// 536.499 us; speedup vs baseline: 1.3062x; 1.3062x over previous
//
#include <hip/hip_runtime.h>
#include <math.h>

namespace {
constexpr int kH = 384, kW = 384, kBn = 2;
constexpr int kHW = kH * kW;       // 147456
constexpr int kOMD = 112;
constexpr int kNB = kBn * (kHW / 64);   // 4608 blocks
constexpr int kNB8 = kNB / 8;           // 576 per XCD
}

__device__ __forceinline__ int swz(int bid) {
    // XCD-aware: round-robin dispatch -> each XCD gets a contiguous range
    return (bid & 7) * kNB8 + (bid >> 3);
}

__device__ __forceinline__ void fma4(float* acc, float a, float4 w) {
    acc[0] = fmaf(a, w.x, acc[0]);
    acc[1] = fmaf(a, w.y, acc[1]);
    acc[2] = fmaf(a, w.z, acc[2]);
    acc[3] = fmaf(a, w.w, acc[3]);
}

// K1: value[b,h,w,c] = sum_ci inp[b,ci,h,w] * Wv[ci,c] + bv[c]
// thread (tp,tc): 4 pixels x 4 channels; coalesced float4 stores.
__global__ __launch_bounds__(256, 4) void k_value(
        const float* __restrict__ inp, const float* __restrict__ Wv,
        const float* __restrict__ bv, float* __restrict__ value) {
    __shared__ float xin[64][65];   // [p][ci] (+1 pad)
    __shared__ float wv[64 * 64];   // [ci][co]
    const int tid = threadIdx.x;
    const int bid = swz(blockIdx.x);
    const int b = bid / (kHW / 64);
    const int pix0 = (bid % (kHW / 64)) * 64;
    const float* ib = inp + (size_t)b * 64 * kHW + pix0;
    for (int i = tid; i < 4096; i += 256) {
        const int c = i >> 6, p = i & 63;
        xin[p][c] = ib[(size_t)c * kHW + p];
        wv[i] = Wv[i];
    }
    __syncthreads();
    const int tc = tid & 15, tp = tid >> 4;   // c0 = tc*4, p0 = tp*4
    float acc[4][4];
    {
        const float4 b4 = *(const float4*)(bv + tc * 4);
        #pragma unroll
        for (int q = 0; q < 4; ++q) {
            acc[q][0] = b4.x; acc[q][1] = b4.y; acc[q][2] = b4.z; acc[q][3] = b4.w;
        }
    }
    #pragma unroll 4
    for (int ci = 0; ci < 64; ++ci) {
        const float4 w4 = *(const float4*)&wv[ci * 64 + tc * 4];
        #pragma unroll
        for (int q = 0; q < 4; ++q) {
            fma4(acc[q], xin[tp * 4 + q][ci], w4);
        }
    }
    #pragma unroll
    for (int q = 0; q < 4; ++q) {
        float4* vo = (float4*)(value +
                ((size_t)b * kHW + pix0 + tp * 4 + q) * 64 + tc * 4);
        *vo = make_float4(acc[q][0], acc[q][1], acc[q][2], acc[q][3]);
    }
}

// K2: fused depthwise conv -> om matvec -> deformable sampling -> @Wo -> out
// One block = 64 consecutive pixels of one row. 256 threads.
__global__ __launch_bounds__(256, 4) void k_main(
        const float* __restrict__ inp, const float* __restrict__ Wdw,
        const float* __restrict__ bdw, const float* __restrict__ Wom,
        const float* __restrict__ bom, const float* __restrict__ Wo,
        const float* __restrict__ value, float* __restrict__ out) {
    __shared__ float lds1[64][68];   // dw^T [c][p]; later reused as sampled^T [c][p]

    const int tid = threadIdx.x;
    const int bid = swz(blockIdx.x);
    const int b = bid / (kH * (kW / 64));
    const int rem = bid % (kH * (kW / 64));
    const int h = rem / (kW / 64);
    const int w0 = (rem % (kW / 64)) * 64;

    const int p = tid & 63;
    const int g = tid >> 6;
    const int gs = __builtin_amdgcn_readfirstlane(g);   // wave-uniform -> SGPR

    // ---- stage A: depthwise 3x3 conv (zero pad) -> lds1[c][p] ----
    {
        const int w = w0 + p;
        #pragma unroll 4
        for (int cc = 0; cc < 16; ++cc) {
            const int c = gs * 16 + cc;                 // wave-uniform
            const float* ib = inp + (size_t)(b * 64 + c) * kHW;
            float s = bdw[c];
            #pragma unroll
            for (int r = 0; r < 3; ++r) {
                const int y = h - 1 + r;
                if (y >= 0 && y < kH) {
                    const float* rowp = ib + (size_t)y * kW;
                    #pragma unroll
                    for (int kx = 0; kx < 3; ++kx) {
                        const int x = w - 1 + kx;
                        const float v = (x >= 0 && x < kW) ? rowp[x] : 0.f;
                        s = fmaf(v, Wdw[c * 9 + r * 3 + kx], s);
                    }
                }
            }
            lds1[c][p] = s;
        }
    }
    __syncthreads();

    // ---- stage B: om[27] for this (pixel p, group g), in registers ----
    // om[j] = sum_ci dw[p][ci] * Wom[ci][gs*27+j] + bom[gs*27+j]
    float om[27];
    {
        const float* bg = bom + gs * 27;                // scalar loads
        #pragma unroll
        for (int j = 0; j < 27; ++j) om[j] = bg[j];
        #pragma unroll 2
        for (int ci = 0; ci < 64; ++ci) {
            const float a = lds1[ci][p];
            const float* wr = Wom + ci * kOMD + gs * 27;  // wave-uniform -> s_load
            #pragma unroll
            for (int j = 0; j < 27; ++j) om[j] = fmaf(a, wr[j], om[j]);
        }
    }
    __syncthreads();   // lds1 reads done; stage C will overwrite it

    // ---- stage C: deformable bilinear sampling ----
    {
        float acc[16];
        #pragma unroll
        for (int j = 0; j < 16; ++j) acc[j] = 0.f;
        const float fw = (float)(w0 + p);
        const float fh = (float)h;
        const float* vbase = value + (size_t)b * kHW * 64 + gs * 16;
        #pragma unroll
        for (int k = 0; k < 9; ++k) {
            const int ky = k / 3, kx = k % 3;
            const float dx = om[2 * k];
            const float dy = om[2 * k + 1];
            const float m = om[18 + k];
            const float px = fw + (float)(kx - 1) + dx;
            const float py = fh + (float)(ky - 1) + dy;
            const float x0f = floorf(px), y0f = floorf(py);
            const int x0 = (int)x0f, y0 = (int)y0f;
            const float wx1 = px - x0f, wy1 = py - y0f;
            const float wx0 = 1.f - wx1, wy0 = 1.f - wy1;
            #pragma unroll
            for (int cor = 0; cor < 4; ++cor) {
                const int dy2 = cor >> 1, dx2 = cor & 1;
                const int xi = x0 + dx2, yi = y0 + dy2;
                float wgt = (dy2 ? wy1 : wy0) * (dx2 ? wx1 : wx0) * m;
                if (xi < 0 || xi >= kW || yi < 0 || yi >= kH) wgt = 0.f;
                const int xc = min(max(xi, 0), kW - 1);
                const int yc = min(max(yi, 0), kH - 1);
                const float4* vp = (const float4*)(vbase +
                        ((size_t)yc * kW + xc) * 64);
                fma4(acc + 0, wgt, vp[0]);
                fma4(acc + 4, wgt, vp[1]);
                fma4(acc + 8, wgt, vp[2]);
                fma4(acc + 12, wgt, vp[3]);
            }
        }
        // write sampled result transposed into lds1 (dw is dead now)
        #pragma unroll
        for (int j = 0; j < 16; ++j) lds1[gs * 16 + j][p] = acc[j];
    }
    __syncthreads();

    // ---- stage D: final @Wo, coalesced (B,C,H,W) writeout ----
    {
        const int cg = gs;                              // wave-uniform
        float acc[16];
        #pragma unroll
        for (int j = 0; j < 16; ++j) acc[j] = 0.f;
        #pragma unroll 4
        for (int ci = 0; ci < 64; ++ci) {
            const float a = lds1[ci][p];
            const float* wr = Wo + ci * 64 + cg * 16;   // wave-uniform -> s_load
            #pragma unroll
            for (int j = 0; j < 16; ++j) acc[j] = fmaf(a, wr[j], acc[j]);
        }
        float* ob = out + (size_t)(b * 64 + cg * 16) * kHW + (size_t)h * kW + w0 + p;
        #pragma unroll
        for (int j = 0; j < 16; ++j) ob[(size_t)j * kHW] = acc[j];
    }
}

extern "C" void kernel_launch(void* const* d_in, const int* in_sizes, int n_in,
                              void* d_out, int out_size, void* d_ws, size_t ws_size,
                              hipStream_t stream) {
    const float* inp = (const float*)d_in[0];
    const float* Wv  = (const float*)d_in[1];
    const float* bv  = (const float*)d_in[2];
    const float* Wdw = (const float*)d_in[3];
    const float* bdw = (const float*)d_in[4];
    const float* Wom = (const float*)d_in[5];
    const float* bom = (const float*)d_in[6];
    const float* Wo  = (const float*)d_in[7];
    float* outp  = (float*)d_out;
    float* value = (float*)d_ws;    // (B,H,W,64) fp32 = 75.5 MB

    k_value<<<kNB, 256, 0, stream>>>(inp, Wv, bv, value);
    k_main<<<kNB, 256, 0, stream>>>(inp, Wdw, bdw, Wom, bom, Wo, value, outp);
}

// Round 3
// 326.886 us; speedup vs baseline: 2.1439x; 1.6412x over previous
//
#include <hip/hip_runtime.h>
#include <hip/hip_bf16.h>
#include <math.h>

namespace {
constexpr int kH = 384, kW = 384, kBn = 2;
constexpr int kHW = kH * kW;       // 147456
constexpr int kOMD = 112;
constexpr int kNB = kBn * (kHW / 64);   // 4608 blocks
constexpr int kNB8 = kNB / 8;           // 576 per XCD
}

__device__ __forceinline__ int swz(int bid) {
    // XCD-aware: round-robin dispatch -> each XCD gets a contiguous range
    return (bid & 7) * kNB8 + (bid >> 3);
}

__device__ __forceinline__ void fma4(float* acc, float a, float4 w) {
    acc[0] = fmaf(a, w.x, acc[0]);
    acc[1] = fmaf(a, w.y, acc[1]);
    acc[2] = fmaf(a, w.z, acc[2]);
    acc[3] = fmaf(a, w.w, acc[3]);
}

// bf16 pair unpack (packed in a uint32: low ushort = even channel, high = odd)
__device__ __forceinline__ float bl(unsigned u) {
    return __uint_as_float(u << 16);
}
__device__ __forceinline__ float bh(unsigned u) {
    return __uint_as_float(u & 0xffff0000u);
}
__device__ __forceinline__ unsigned short f2bf(float f) {
    union { __hip_bfloat16 b; unsigned short s; } u;
    u.b = __float2bfloat16(f);   // RNE
    return u.s;
}

// K1: value[b][g][yx][c16] (bf16) = inp(b,:,yx) @ Wv + bv
// thread (tp,tc): 4 pixels x 4 channels; fp32 compute, bf16 store.
__global__ __launch_bounds__(256) void k_value(
        const float* __restrict__ inp, const float* __restrict__ Wv,
        const float* __restrict__ bv, unsigned short* __restrict__ value) {
    __shared__ float xin[64][65];   // [p][ci] (+1 pad)
    __shared__ float wv[64 * 64];   // [ci][co]
    const int tid = threadIdx.x;
    const int bid = swz(blockIdx.x);
    const int b = bid / (kHW / 64);
    const int pix0 = (bid % (kHW / 64)) * 64;
    const float* ib = inp + (size_t)b * 64 * kHW + pix0;
    for (int i = tid; i < 4096; i += 256) {
        const int c = i >> 6, p = i & 63;
        xin[p][c] = ib[(size_t)c * kHW + p];
        wv[i] = Wv[i];
    }
    __syncthreads();
    const int tc = tid & 15, tp = tid >> 4;   // c0 = tc*4, p0 = tp*4
    float acc[4][4];
    {
        const float4 b4 = *(const float4*)(bv + tc * 4);
        #pragma unroll
        for (int q = 0; q < 4; ++q) {
            acc[q][0] = b4.x; acc[q][1] = b4.y; acc[q][2] = b4.z; acc[q][3] = b4.w;
        }
    }
    #pragma unroll 4
    for (int ci = 0; ci < 64; ++ci) {
        const float4 w4 = *(const float4*)&wv[ci * 64 + tc * 4];
        #pragma unroll
        for (int q = 0; q < 4; ++q) {
            fma4(acc[q], xin[tp * 4 + q][ci], w4);
        }
    }
    const int g = tc >> 2, cq = tc & 3;
    #pragma unroll
    for (int q = 0; q < 4; ++q) {
        ushort4 st;
        st.x = f2bf(acc[q][0]); st.y = f2bf(acc[q][1]);
        st.z = f2bf(acc[q][2]); st.w = f2bf(acc[q][3]);
        ushort4* vo = (ushort4*)(value +
                ((size_t)(b * 4 + g) * kHW + pix0 + tp * 4 + q) * 16 + cq * 4);
        *vo = st;
    }
}

// K2: fused depthwise conv -> om matvec -> deformable sampling -> @Wo -> out
// One block = 64 consecutive pixels of one row. 256 threads.
__global__ __launch_bounds__(256) void k_main(
        const float* __restrict__ inp, const float* __restrict__ Wdw,
        const float* __restrict__ bdw, const float* __restrict__ Wom,
        const float* __restrict__ bom, const float* __restrict__ Wo,
        const unsigned short* __restrict__ value, float* __restrict__ out) {
    __shared__ float lds1[64][68];   // dw^T [c][p]; later reused as sampled^T [c][p]

    const int tid = threadIdx.x;
    const int bid = swz(blockIdx.x);
    const int b = bid / (kH * (kW / 64));
    const int rem = bid % (kH * (kW / 64));
    const int h = rem / (kW / 64);
    const int w0 = (rem % (kW / 64)) * 64;

    const int p = tid & 63;
    const int g = tid >> 6;
    const int gs = __builtin_amdgcn_readfirstlane(g);   // wave-uniform -> SGPR

    // ---- stage A: depthwise 3x3 conv (zero pad) -> lds1[c][p] ----
    {
        const int w = w0 + p;
        #pragma unroll 4
        for (int cc = 0; cc < 16; ++cc) {
            const int c = gs * 16 + cc;                 // wave-uniform
            const float* ib = inp + (size_t)(b * 64 + c) * kHW;
            float s = bdw[c];
            #pragma unroll
            for (int r = 0; r < 3; ++r) {
                const int y = h - 1 + r;
                if (y >= 0 && y < kH) {
                    const float* rowp = ib + (size_t)y * kW;
                    #pragma unroll
                    for (int kx = 0; kx < 3; ++kx) {
                        const int x = w - 1 + kx;
                        const float v = (x >= 0 && x < kW) ? rowp[x] : 0.f;
                        s = fmaf(v, Wdw[c * 9 + r * 3 + kx], s);
                    }
                }
            }
            lds1[c][p] = s;
        }
    }
    __syncthreads();

    // ---- stage B: om[27] for this (pixel p, group g), in registers ----
    float om[27];
    {
        const float* bg = bom + gs * 27;                // scalar loads
        #pragma unroll
        for (int j = 0; j < 27; ++j) om[j] = bg[j];
        #pragma unroll 4
        for (int ci = 0; ci < 64; ++ci) {
            const float a = lds1[ci][p];
            const float* wr = Wom + ci * kOMD + gs * 27;  // wave-uniform -> s_load
            #pragma unroll
            for (int j = 0; j < 27; ++j) om[j] = fmaf(a, wr[j], om[j]);
        }
    }
    __syncthreads();   // lds1 reads done; stage C will overwrite it

    // ---- stage C: deformable bilinear sampling (bf16 value, 32B/corner) ----
    {
        float acc[16];
        #pragma unroll
        for (int j = 0; j < 16; ++j) acc[j] = 0.f;
        const float fw = (float)(w0 + p);
        const float fh = (float)h;
        const unsigned short* vbase = value + (size_t)(b * 4 + gs) * kHW * 16;
        #pragma unroll
        for (int k = 0; k < 9; ++k) {
            const int ky = k / 3, kx = k % 3;
            const float dx = om[2 * k];
            const float dy = om[2 * k + 1];
            const float m = om[18 + k];
            const float px = fw + (float)(kx - 1) + dx;
            const float py = fh + (float)(ky - 1) + dy;
            const float x0f = floorf(px), y0f = floorf(py);
            const int x0 = (int)x0f, y0 = (int)y0f;
            const float wx1 = px - x0f, wy1 = py - y0f;
            const float wx0 = 1.f - wx1, wy0 = 1.f - wy1;
            #pragma unroll
            for (int cor = 0; cor < 4; ++cor) {
                const int dy2 = cor >> 1, dx2 = cor & 1;
                const int xi = x0 + dx2, yi = y0 + dy2;
                float wgt = (dy2 ? wy1 : wy0) * (dx2 ? wx1 : wx0) * m;
                if (xi < 0 || xi >= kW || yi < 0 || yi >= kH) wgt = 0.f;
                const int xc = min(max(xi, 0), kW - 1);
                const int yc = min(max(yi, 0), kH - 1);
                const uint4* vp = (const uint4*)(vbase +
                        ((size_t)yc * kW + xc) * 16);
                const uint4 u0 = vp[0];
                const uint4 u1 = vp[1];
                acc[0]  = fmaf(wgt, bl(u0.x), acc[0]);
                acc[1]  = fmaf(wgt, bh(u0.x), acc[1]);
                acc[2]  = fmaf(wgt, bl(u0.y), acc[2]);
                acc[3]  = fmaf(wgt, bh(u0.y), acc[3]);
                acc[4]  = fmaf(wgt, bl(u0.z), acc[4]);
                acc[5]  = fmaf(wgt, bh(u0.z), acc[5]);
                acc[6]  = fmaf(wgt, bl(u0.w), acc[6]);
                acc[7]  = fmaf(wgt, bh(u0.w), acc[7]);
                acc[8]  = fmaf(wgt, bl(u1.x), acc[8]);
                acc[9]  = fmaf(wgt, bh(u1.x), acc[9]);
                acc[10] = fmaf(wgt, bl(u1.y), acc[10]);
                acc[11] = fmaf(wgt, bh(u1.y), acc[11]);
                acc[12] = fmaf(wgt, bl(u1.z), acc[12]);
                acc[13] = fmaf(wgt, bh(u1.z), acc[13]);
                acc[14] = fmaf(wgt, bl(u1.w), acc[14]);
                acc[15] = fmaf(wgt, bh(u1.w), acc[15]);
            }
        }
        // write sampled result transposed into lds1 (dw is dead now)
        #pragma unroll
        for (int j = 0; j < 16; ++j) lds1[gs * 16 + j][p] = acc[j];
    }
    __syncthreads();

    // ---- stage D: final @Wo, coalesced (B,C,H,W) writeout ----
    {
        const int cg = gs;                              // wave-uniform
        float acc[16];
        #pragma unroll
        for (int j = 0; j < 16; ++j) acc[j] = 0.f;
        #pragma unroll 4
        for (int ci = 0; ci < 64; ++ci) {
            const float a = lds1[ci][p];
            const float* wr = Wo + ci * 64 + cg * 16;   // wave-uniform -> s_load
            #pragma unroll
            for (int j = 0; j < 16; ++j) acc[j] = fmaf(a, wr[j], acc[j]);
        }
        float* ob = out + (size_t)(b * 64 + cg * 16) * kHW + (size_t)h * kW + w0 + p;
        #pragma unroll
        for (int j = 0; j < 16; ++j) ob[(size_t)j * kHW] = acc[j];
    }
}

extern "C" void kernel_launch(void* const* d_in, const int* in_sizes, int n_in,
                              void* d_out, int out_size, void* d_ws, size_t ws_size,
                              hipStream_t stream) {
    const float* inp = (const float*)d_in[0];
    const float* Wv  = (const float*)d_in[1];
    const float* bv  = (const float*)d_in[2];
    const float* Wdw = (const float*)d_in[3];
    const float* bdw = (const float*)d_in[4];
    const float* Wom = (const float*)d_in[5];
    const float* bom = (const float*)d_in[6];
    const float* Wo  = (const float*)d_in[7];
    float* outp = (float*)d_out;
    unsigned short* value = (unsigned short*)d_ws;   // [b][g][yx][16] bf16 = 37.7 MB

    k_value<<<kNB, 256, 0, stream>>>(inp, Wv, bv, value);
    k_main<<<kNB, 256, 0, stream>>>(inp, Wdw, bdw, Wom, bom, Wo, value, outp);
}